// Round 7
// baseline (595.417 us; speedup 1.0000x reference)
//
#include <hip/hip_runtime.h>
#include <hip/hip_bf16.h>
#include <math.h>

#define NROWS 16384
#define HID 64
#define KSPLIT 8
#define KCH (NROWS / KSPLIT)  // 2048
#define NSTEP (KCH / 32)      // 64

typedef __attribute__((ext_vector_type(8))) __bf16 bf16x8;
typedef __attribute__((ext_vector_type(4))) float f32x4;

__device__ inline f32x4 mfma16(bf16x8 a, bf16x8 b, f32x4 c) {
    return __builtin_amdgcn_mfma_f32_16x16x32_bf16(a, b, c, 0, 0, 0);
}

__device__ inline void split8v(const f32x4 v0, const f32x4 v1, bf16x8& h, bf16x8& l) {
    float f[8] = {v0[0], v0[1], v0[2], v0[3], v1[0], v1[1], v1[2], v1[3]};
#pragma unroll
    for (int j = 0; j < 8; ++j) {
        __bf16 hh = (__bf16)f[j];
        h[j] = hh;
        l[j] = (__bf16)(f[j] - (float)hh);
    }
}

// ---------------------------------------------------------------------------
// pack_b: x [16384,64] fp32 row-major  ->  MFMA B-fragment-ordered bf16 hi/lo.
// Packed index: (((kb*4 + t)*64 + lane)*8 + j)
//   holds x[kb*32 + (lane>>4)*8 + j][t*16 + (lane&15)]
// ---------------------------------------------------------------------------
__global__ __launch_bounds__(256) void pack_b(const float* __restrict__ x,
                                              __bf16* __restrict__ hi,
                                              __bf16* __restrict__ lo) {
    __shared__ float tile[32 * 64];
    const int kb = blockIdx.x;  // 0..511, 32 k-rows each
    const f32x4* src = (const f32x4*)(x + (size_t)kb * 32 * 64);
    f32x4* dst = (f32x4*)tile;
    dst[threadIdx.x] = src[threadIdx.x];
    dst[threadIdx.x + 256] = src[threadIdx.x + 256];
    __syncthreads();
    const int t = threadIdx.x >> 6;    // n-tile 0..3
    const int l = threadIdx.x & 63;    // consumer lane
    const int col = (t << 4) + (l & 15);
    const int krow = (l >> 4) * 8;
    bf16x8 h8, l8;
#pragma unroll
    for (int j = 0; j < 8; ++j) {
        float v = tile[(krow + j) * 64 + col];
        __bf16 hh = (__bf16)v;
        h8[j] = hh;
        l8[j] = (__bf16)(v - (float)hh);
    }
    const size_t base = (((size_t)kb * 4 + t) * 64 + l) * 8;
    *(bf16x8*)(hi + base) = h8;
    *(bf16x8*)(lo + base) = l8;
}

// ---------------------------------------------------------------------------
// gemm_partial: partial[ks] = adj[:, ks-chunk] @ x[ks-chunk, :]
// blockIdx = ks*64 + rt. Block = 256 rows x 2048 k; 8 waves x 32 rows
// (2 row-groups of 16), ALL waves share the same k-range -> B fragments
// L1-shared across 8 waves; logical B traffic 256 MB/gemm (was 512 MB).
// K-phase stagger: block starts its sweep at step (blockIdx&7)*8 (wrap).
// Same-XCD blocks (blockIdx%8) share a phase -> per-XCD B window stays
// small/L2-warm; the 8 XCDs hit 8 distinct DRAM column regions -> avoids
// the all-blocks-at-column-0 channel hotspot.
// adj loads plain (L1 merges the half-line pair; nt double-fetched, r3/r4).
// Partial stores nt (no reuse, keep L2 for B).
// ---------------------------------------------------------------------------
__global__ __launch_bounds__(512, 4) void gemm_partial(const float* __restrict__ adj,
                                                       const __bf16* __restrict__ Bhi,
                                                       const __bf16* __restrict__ Blo,
                                                       float* __restrict__ partial) {
    const int lane = threadIdx.x & 63;
    const int wv = threadIdx.x >> 6;   // wave -> 32-row group (0..7)
    const int rt = blockIdx.x & 63;    // row-tile 0..63 (256 rows each)
    const int ks = blockIdx.x >> 6;    // k-split 0..7
    const int rbase = rt * 256 + wv * 32;
    const int rq = lane & 15;          // A row within 16-row group
    const int kq = lane >> 4;          // k-quarter 0..3
    const int phase = (blockIdx.x & 7) * (NSTEP / 8);

    f32x4 acc[2][4];
#pragma unroll
    for (int g = 0; g < 2; ++g)
#pragma unroll
        for (int t = 0; t < 4; ++t) acc[g][t] = f32x4{0.f, 0.f, 0.f, 0.f};

    const float* a0p = adj + (size_t)(rbase + rq) * NROWS + ks * KCH + kq * 8;
    const float* a1p = a0p + (size_t)16 * NROWS;
    const int kk0 = ks * KCH;

    for (int s = 0; s < NSTEP; ++s) {
        const int kk = ((s + phase) & (NSTEP - 1)) * 32;
        // B fragments (L2-resident packed bf16), 8 x 16B loads, wave-shared
        const size_t bb = ((size_t)((kk0 + kk) >> 5) * 4) * 512 + (size_t)lane * 8;
        bf16x8 bh[4], bl[4];
#pragma unroll
        for (int t = 0; t < 4; ++t) {
            bh[t] = *(const bf16x8*)(Bhi + bb + (size_t)t * 512);
            bl[t] = *(const bf16x8*)(Blo + bb + (size_t)t * 512);
        }
        // A: two 16-row groups, 8 fp32 per lane each, contiguous 32B
        const f32x4* a0 = (const f32x4*)(a0p + kk);
        const f32x4* a1 = (const f32x4*)(a1p + kk);
        f32x4 v0 = a0[0], v1 = a0[1];
        f32x4 w0 = a1[0], w1 = a1[1];
        bf16x8 ah0, al0, ah1, al1;
        split8v(v0, v1, ah0, al0);
        split8v(w0, w1, ah1, al1);

#pragma unroll
        for (int t = 0; t < 4; ++t) {
            acc[0][t] = mfma16(ah0, bh[t], acc[0][t]);
            acc[0][t] = mfma16(ah0, bl[t], acc[0][t]);
            acc[0][t] = mfma16(al0, bh[t], acc[0][t]);
            acc[1][t] = mfma16(ah1, bh[t], acc[1][t]);
            acc[1][t] = mfma16(ah1, bl[t], acc[1][t]);
            acc[1][t] = mfma16(al1, bh[t], acc[1][t]);
        }
    }

    // C/D layout: col = lane&15, row = (lane>>4)*4 + reg   [m89-verified]
    float* pp = partial + (size_t)ks * (NROWS * HID) + (size_t)rbase * HID;
#pragma unroll
    for (int g = 0; g < 2; ++g)
#pragma unroll
        for (int t = 0; t < 4; ++t)
#pragma unroll
            for (int r = 0; r < 4; ++r)
                __builtin_nontemporal_store(acc[g][t][r],
                    pp + (g * 16 + kq * 4 + r) * HID + t * 16 + (lane & 15));
}

// ---------------------------------------------------------------------------
// reduce_dense: agg_r = sum_ks partial[ks][r]; x_out[r] = tanh([agg_r|x_r] @ W)
// W [128,64] staged in LDS; lane = output column; row values via __shfl.
// ---------------------------------------------------------------------------
__global__ __launch_bounds__(256) void reduce_dense(const float* __restrict__ partial,
                                                    const float* __restrict__ xin,
                                                    const float* __restrict__ W,
                                                    float* __restrict__ xout) {
    __shared__ float wsm[128 * 64];  // 32 KB
    const f32x4* wsrc = (const f32x4*)W;
    f32x4* wdst = (f32x4*)wsm;
#pragma unroll
    for (int i = 0; i < 8; ++i) wdst[threadIdx.x + 256 * i] = wsrc[threadIdx.x + 256 * i];
    __syncthreads();

    const int lane = threadIdx.x & 63;
    const int wv = threadIdx.x >> 6;
    const int r0 = blockIdx.x * 32 + wv * 8;
#pragma unroll 2
    for (int i = 0; i < 8; ++i) {
        const int r = r0 + i;
        float av = 0.f;
#pragma unroll
        for (int ks = 0; ks < KSPLIT; ++ks)
            av += partial[(size_t)ks * (NROWS * HID) + (size_t)r * HID + lane];
        const float xv = xin[(size_t)r * HID + lane];
        float z = 0.f;
#pragma unroll
        for (int j = 0; j < 64; ++j) z += __shfl(av, j) * wsm[j * 64 + lane];
#pragma unroll
        for (int j = 0; j < 64; ++j) z += __shfl(xv, j) * wsm[(64 + j) * 64 + lane];
        xout[(size_t)r * HID + lane] = tanhf(z);
    }
}

extern "C" void kernel_launch(void* const* d_in, const int* in_sizes, int n_in,
                              void* d_out, int out_size, void* d_ws, size_t ws_size,
                              hipStream_t stream) {
    const float* x0 = (const float*)d_in[0];   // user_embs [16384,64]
    const float* adj = (const float*)d_in[1];  // adj [16384,16384]
    const float* W = (const float*)d_in[2];    // W [2,128,64]
    float* out = (float*)d_out;

    char* ws = (char*)d_ws;
    __bf16* Bhi = (__bf16*)(ws);                       // 2 MB
    __bf16* Blo = (__bf16*)(ws + (2u << 20));          // 2 MB
    float* partial = (float*)(ws + (4u << 20));        // 32 MB (8 x 4 MB)
    float* x1 = (float*)(ws + (36u << 20));            // 4 MB

    // hop 0
    pack_b<<<512, 256, 0, stream>>>(x0, Bhi, Blo);
    gemm_partial<<<KSPLIT * 64, 512, 0, stream>>>(adj, Bhi, Blo, partial);
    reduce_dense<<<512, 256, 0, stream>>>(partial, x0, W, x1);
    // hop 1
    pack_b<<<512, 256, 0, stream>>>(x1, Bhi, Blo);
    gemm_partial<<<KSPLIT * 64, 512, 0, stream>>>(adj, Bhi, Blo, partial);
    reduce_dense<<<512, 256, 0, stream>>>(partial, x1, W + 128 * 64, out);
}

// Round 8
// 588.208 us; speedup vs baseline: 1.0123x; 1.0123x over previous
//
#include <hip/hip_runtime.h>
#include <hip/hip_bf16.h>
#include <math.h>

#define NROWS 16384
#define HID 64
#define KSPLIT 8
#define KCH (NROWS / KSPLIT)  // 2048

typedef __attribute__((ext_vector_type(8))) __bf16 bf16x8;
typedef __attribute__((ext_vector_type(4))) float f32x4;

__device__ inline f32x4 mfma16(bf16x8 a, bf16x8 b, f32x4 c) {
    return __builtin_amdgcn_mfma_f32_16x16x32_bf16(a, b, c, 0, 0, 0);
}

__device__ inline void split8v(const f32x4 v0, const f32x4 v1, bf16x8& h, bf16x8& l) {
    float f[8] = {v0[0], v0[1], v0[2], v0[3], v1[0], v1[1], v1[2], v1[3]};
#pragma unroll
    for (int j = 0; j < 8; ++j) {
        __bf16 hh = (__bf16)f[j];
        h[j] = hh;
        l[j] = (__bf16)(f[j] - (float)hh);
    }
}

// ---------------------------------------------------------------------------
// pack_b: x [16384,64] fp32 row-major  ->  MFMA B-fragment-ordered bf16 hi/lo.
// Packed index: (((kb*4 + t)*64 + lane)*8 + j)
//   holds x[kb*32 + (lane>>4)*8 + j][t*16 + (lane&15)]
// ---------------------------------------------------------------------------
__global__ __launch_bounds__(256) void pack_b(const float* __restrict__ x,
                                              __bf16* __restrict__ hi,
                                              __bf16* __restrict__ lo) {
    __shared__ float tile[32 * 64];
    const int kb = blockIdx.x;  // 0..511, 32 k-rows each
    const f32x4* src = (const f32x4*)(x + (size_t)kb * 32 * 64);
    f32x4* dst = (f32x4*)tile;
    dst[threadIdx.x] = src[threadIdx.x];
    dst[threadIdx.x + 256] = src[threadIdx.x + 256];
    __syncthreads();
    const int t = threadIdx.x >> 6;    // n-tile 0..3
    const int l = threadIdx.x & 63;    // consumer lane
    const int col = (t << 4) + (l & 15);
    const int krow = (l >> 4) * 8;
    bf16x8 h8, l8;
#pragma unroll
    for (int j = 0; j < 8; ++j) {
        float v = tile[(krow + j) * 64 + col];
        __bf16 hh = (__bf16)v;
        h8[j] = hh;
        l8[j] = (__bf16)(v - (float)hh);
    }
    const size_t base = (((size_t)kb * 4 + t) * 64 + l) * 8;
    *(bf16x8*)(hi + base) = h8;
    *(bf16x8*)(lo + base) = l8;
}

// ---------------------------------------------------------------------------
// gemm_partial: partial[ks] = adj[:, ks-chunk] @ x[ks-chunk, :]
// r6 structure (blockIdx = ks*128 + rt; 128 rows x 2048 k per block; 4 waves
// x 32 rows sharing the k-range) + ONE change: the k-loop is unrolled x4 and
// all 16 A-load instructions are batch-issued back-to-back. Each adj row now
// gets 4 consecutive 128B line requests (512B) within a few dozen cycles ->
// one DRAM page visit instead of 4 separate activations. (r6/r7 showed the
// gap is NOT occupancy / B-refetch / channel phase; this targets page-open
// efficiency, the remaining structural difference vs the 6.5 TB/s fill.)
// adj loads plain (L1 merges half-line pairs; nt double-fetched, r3/r4).
// Partial stores nt (no reuse, keep L2 for B).
// ---------------------------------------------------------------------------
__global__ __launch_bounds__(256, 3) void gemm_partial(const float* __restrict__ adj,
                                                       const __bf16* __restrict__ Bhi,
                                                       const __bf16* __restrict__ Blo,
                                                       float* __restrict__ partial) {
    const int lane = threadIdx.x & 63;
    const int wv = threadIdx.x >> 6;   // wave -> 32-row group (0..3)
    const int rt = blockIdx.x & 127;   // row-tile 0..127 (128 rows each)
    const int ks = blockIdx.x >> 7;    // k-split 0..7
    const int rbase = rt * 128 + wv * 32;
    const int rq = lane & 15;          // A row within 16-row group
    const int kq = lane >> 4;          // k-quarter 0..3

    f32x4 acc[2][4];
#pragma unroll
    for (int g = 0; g < 2; ++g)
#pragma unroll
        for (int t = 0; t < 4; ++t) acc[g][t] = f32x4{0.f, 0.f, 0.f, 0.f};

    const float* a0p = adj + (size_t)(rbase + rq) * NROWS + ks * KCH + kq * 8;
    const float* a1p = a0p + (size_t)16 * NROWS;
    const int kk0 = ks * KCH;

    for (int kk = 0; kk < KCH; kk += 128) {
        // ---- A batch: 16 load instructions issued back-to-back ----
        // Per 16-row group and sub-step u, lanes cover rows' bytes
        // [u*128, u*128+128) -> 4 consecutive lines per row per batch.
        f32x4 va[4][2], wa[4][2];
#pragma unroll
        for (int u = 0; u < 4; ++u) {
            const f32x4* p0 = (const f32x4*)(a0p + kk + u * 32);
            va[u][0] = p0[0];
            va[u][1] = p0[1];
        }
#pragma unroll
        for (int u = 0; u < 4; ++u) {
            const f32x4* p1 = (const f32x4*)(a1p + kk + u * 32);
            wa[u][0] = p1[0];
            wa[u][1] = p1[1];
        }
        // ---- consume 4 sub-steps ----
#pragma unroll
        for (int u = 0; u < 4; ++u) {
            const size_t bb =
                ((size_t)((kk0 + kk + u * 32) >> 5) * 4) * 512 + (size_t)lane * 8;
            bf16x8 bh[4], bl[4];
#pragma unroll
            for (int t = 0; t < 4; ++t) {
                bh[t] = *(const bf16x8*)(Bhi + bb + (size_t)t * 512);
                bl[t] = *(const bf16x8*)(Blo + bb + (size_t)t * 512);
            }
            bf16x8 ah0, al0, ah1, al1;
            split8v(va[u][0], va[u][1], ah0, al0);
            split8v(wa[u][0], wa[u][1], ah1, al1);
#pragma unroll
            for (int t = 0; t < 4; ++t) {
                acc[0][t] = mfma16(ah0, bh[t], acc[0][t]);
                acc[0][t] = mfma16(ah0, bl[t], acc[0][t]);
                acc[0][t] = mfma16(al0, bh[t], acc[0][t]);
                acc[1][t] = mfma16(ah1, bh[t], acc[1][t]);
                acc[1][t] = mfma16(ah1, bl[t], acc[1][t]);
                acc[1][t] = mfma16(al1, bh[t], acc[1][t]);
            }
        }
    }

    // C/D layout: col = lane&15, row = (lane>>4)*4 + reg   [m89-verified]
    float* pp = partial + (size_t)ks * (NROWS * HID) + (size_t)rbase * HID;
#pragma unroll
    for (int g = 0; g < 2; ++g)
#pragma unroll
        for (int t = 0; t < 4; ++t)
#pragma unroll
            for (int r = 0; r < 4; ++r)
                __builtin_nontemporal_store(acc[g][t][r],
                    pp + (g * 16 + kq * 4 + r) * HID + t * 16 + (lane & 15));
}

// ---------------------------------------------------------------------------
// reduce_dense: agg_r = sum_ks partial[ks][r]; x_out[r] = tanh([agg_r|x_r] @ W)
// W [128,64] staged in LDS; lane = output column; row values via __shfl.
// ---------------------------------------------------------------------------
__global__ __launch_bounds__(256) void reduce_dense(const float* __restrict__ partial,
                                                    const float* __restrict__ xin,
                                                    const float* __restrict__ W,
                                                    float* __restrict__ xout) {
    __shared__ float wsm[128 * 64];  // 32 KB
    const f32x4* wsrc = (const f32x4*)W;
    f32x4* wdst = (f32x4*)wsm;
#pragma unroll
    for (int i = 0; i < 8; ++i) wdst[threadIdx.x + 256 * i] = wsrc[threadIdx.x + 256 * i];
    __syncthreads();

    const int lane = threadIdx.x & 63;
    const int wv = threadIdx.x >> 6;
    const int r0 = blockIdx.x * 32 + wv * 8;
#pragma unroll 2
    for (int i = 0; i < 8; ++i) {
        const int r = r0 + i;
        float av = 0.f;
#pragma unroll
        for (int ks = 0; ks < KSPLIT; ++ks)
            av += partial[(size_t)ks * (NROWS * HID) + (size_t)r * HID + lane];
        const float xv = xin[(size_t)r * HID + lane];
        float z = 0.f;
#pragma unroll
        for (int j = 0; j < 64; ++j) z += __shfl(av, j) * wsm[j * 64 + lane];
#pragma unroll
        for (int j = 0; j < 64; ++j) z += __shfl(xv, j) * wsm[(64 + j) * 64 + lane];
        xout[(size_t)r * HID + lane] = tanhf(z);
    }
}

extern "C" void kernel_launch(void* const* d_in, const int* in_sizes, int n_in,
                              void* d_out, int out_size, void* d_ws, size_t ws_size,
                              hipStream_t stream) {
    const float* x0 = (const float*)d_in[0];   // user_embs [16384,64]
    const float* adj = (const float*)d_in[1];  // adj [16384,16384]
    const float* W = (const float*)d_in[2];    // W [2,128,64]
    float* out = (float*)d_out;

    char* ws = (char*)d_ws;
    __bf16* Bhi = (__bf16*)(ws);                       // 2 MB
    __bf16* Blo = (__bf16*)(ws + (2u << 20));          // 2 MB
    float* partial = (float*)(ws + (4u << 20));        // 32 MB (8 x 4 MB)
    float* x1 = (float*)(ws + (36u << 20));            // 4 MB

    // hop 0
    pack_b<<<512, 256, 0, stream>>>(x0, Bhi, Blo);
    gemm_partial<<<KSPLIT * 128, 256, 0, stream>>>(adj, Bhi, Blo, partial);
    reduce_dense<<<512, 256, 0, stream>>>(partial, x0, W, x1);
    // hop 1
    pack_b<<<512, 256, 0, stream>>>(x1, Bhi, Blo);
    gemm_partial<<<KSPLIT * 128, 256, 0, stream>>>(adj, Bhi, Blo, partial);
    reduce_dense<<<512, 256, 0, stream>>>(partial, x1, W + 128 * 64, out);
}

// Round 9
// 587.877 us; speedup vs baseline: 1.0128x; 1.0006x over previous
//
#include <hip/hip_runtime.h>
#include <hip/hip_bf16.h>
#include <math.h>

#define NROWS 16384
#define HID 64
#define KSPLIT 8
#define KCH (NROWS / KSPLIT)   // 2048
#define STK 128                // stage depth in k-floats
#define NSTAGE (KCH / STK)     // 16

typedef __attribute__((ext_vector_type(8))) __bf16 bf16x8;
typedef __attribute__((ext_vector_type(4))) float f32x4;

__device__ inline f32x4 mfma16(bf16x8 a, bf16x8 b, f32x4 c) {
    return __builtin_amdgcn_mfma_f32_16x16x32_bf16(a, b, c, 0, 0, 0);
}

__device__ inline void split8v(const f32x4 v0, const f32x4 v1, bf16x8& h, bf16x8& l) {
    float f[8] = {v0[0], v0[1], v0[2], v0[3], v1[0], v1[1], v1[2], v1[3]};
#pragma unroll
    for (int j = 0; j < 8; ++j) {
        __bf16 hh = (__bf16)f[j];
        h[j] = hh;
        l[j] = (__bf16)(f[j] - (float)hh);
    }
}

// ---------------------------------------------------------------------------
// pack_b: x [16384,64] fp32 row-major  ->  MFMA B-fragment-ordered bf16 hi/lo.
// Packed index: (((kb*4 + t)*64 + lane)*8 + j)
//   holds x[kb*32 + (lane>>4)*8 + j][t*16 + (lane&15)]
// ---------------------------------------------------------------------------
__global__ __launch_bounds__(256) void pack_b(const float* __restrict__ x,
                                              __bf16* __restrict__ hi,
                                              __bf16* __restrict__ lo) {
    __shared__ float tile[32 * 64];
    const int kb = blockIdx.x;  // 0..511, 32 k-rows each
    const f32x4* src = (const f32x4*)(x + (size_t)kb * 32 * 64);
    f32x4* dst = (f32x4*)tile;
    dst[threadIdx.x] = src[threadIdx.x];
    dst[threadIdx.x + 256] = src[threadIdx.x + 256];
    __syncthreads();
    const int t = threadIdx.x >> 6;    // n-tile 0..3
    const int l = threadIdx.x & 63;    // consumer lane
    const int col = (t << 4) + (l & 15);
    const int krow = (l >> 4) * 8;
    bf16x8 h8, l8;
#pragma unroll
    for (int j = 0; j < 8; ++j) {
        float v = tile[(krow + j) * 64 + col];
        __bf16 hh = (__bf16)v;
        h8[j] = hh;
        l8[j] = (__bf16)(v - (float)hh);
    }
    const size_t base = (((size_t)kb * 4 + t) * 64 + l) * 8;
    *(bf16x8*)(hi + base) = h8;
    *(bf16x8*)(lo + base) = l8;
}

// ---------------------------------------------------------------------------
// gemm_partial: partial[ks] = adj[:, ks-chunk] @ x[ks-chunk, :]
// CONTIGUOUS-READ restructure: A is read with lanes-along-k (each wave
// instruction = 2 rows x 512B contiguous runs -- the fill kernel's access
// shape, which demonstrably sustains 6.5 TB/s), staged into LDS, and MFMA
// A-fragments are built by swizzled ds_read_b128. This removes the
// 16-rows-x-128B-scatter per instruction that r2..r8 kept (all scheduling
// fixes on that shape were null -> the shape itself is the theory).
// Block = 32 rows x KCH(2048) k; 4 waves split each stage's 4 k-substeps;
// cross-wave K-reduction via reused LDS. T14 async split: issue A(s+1) ->
// consume(s) -> ds_write(s+1) -> barrier (one barrier/stage, dbuf).
// LDS XOR-swizzle byte^=((row&7)<<4): verified exact 8/bank distribution
// (the 64-lane ds_read_b128 minimum) on both write and read sides.
// ---------------------------------------------------------------------------
__global__ __launch_bounds__(256, 4) void gemm_partial(const float* __restrict__ adj,
                                                       const __bf16* __restrict__ Bhi,
                                                       const __bf16* __restrict__ Blo,
                                                       float* __restrict__ partial) {
    __shared__ char lds_raw[32768];  // 2 x 16KB stage buffers; reused as red

    const int tid = threadIdx.x;
    const int lane = tid & 63;
    const int wv = tid >> 6;          // wave 0..3 -> k-substep within stage
    const int rt = blockIdx.x & 511;  // row-tile (32 rows)
    const int ks = blockIdx.x >> 9;   // k-split 0..7
    const int rbase = rt * 32;
    const int rq = lane & 15;
    const int kq = lane >> 4;

    f32x4 acc[2][4];
#pragma unroll
    for (int g = 0; g < 2; ++g)
#pragma unroll
        for (int t = 0; t < 4; ++t) acc[g][t] = f32x4{0.f, 0.f, 0.f, 0.f};

    // --- staging thread map: thread covers rows (tid>>5)+8i, 16B-chunk tid&31
    const int srow = tid >> 5;
    const int scol = tid & 31;
    const int sw = (srow & 7) << 4;  // swizzle constant (r&7 invariant under +8i)
    const float* agbase = adj + (size_t)(rbase + srow) * NROWS + ks * KCH + scol * 4;

    f32x4 areg[4];
    // prologue: stage 0
#pragma unroll
    for (int i = 0; i < 4; ++i)
        areg[i] = *(const f32x4*)(agbase + (size_t)i * 8 * NROWS);
#pragma unroll
    for (int i = 0; i < 4; ++i)
        *(f32x4*)(lds_raw + (srow + 8 * i) * 512 + ((scol * 16) ^ sw)) = areg[i];
    __syncthreads();

    for (int s = 0; s < NSTAGE; ++s) {
        const int buf = s & 1;
        // issue next stage's A loads (HBM latency hides under consume)
        if (s + 1 < NSTAGE) {
#pragma unroll
            for (int i = 0; i < 4; ++i)
                areg[i] = *(const f32x4*)(agbase + (size_t)i * 8 * NROWS +
                                          (s + 1) * STK);
        }
        // ---- consume stage s: this wave's k-substep = wv ----
        {
            const size_t bb = (size_t)(ks * 64 + s * 4 + wv) * 2048 + (size_t)lane * 8;
            bf16x8 bh[4], bl[4];
#pragma unroll
            for (int t = 0; t < 4; ++t) {
                bh[t] = *(const bf16x8*)(Bhi + bb + (size_t)t * 512);
                bl[t] = *(const bf16x8*)(Blo + bb + (size_t)t * 512);
            }
            char* base = lds_raw + buf * 16384;
            const int kb = wv * 128 + kq * 32;
            const int rsw = (rq & 7) << 4;
            f32x4 a0lo = *(const f32x4*)(base + rq * 512 + (kb ^ rsw));
            f32x4 a0hi = *(const f32x4*)(base + rq * 512 + ((kb + 16) ^ rsw));
            f32x4 a1lo = *(const f32x4*)(base + (16 + rq) * 512 + (kb ^ rsw));
            f32x4 a1hi = *(const f32x4*)(base + (16 + rq) * 512 + ((kb + 16) ^ rsw));
            bf16x8 ah0, al0, ah1, al1;
            split8v(a0lo, a0hi, ah0, al0);
            split8v(a1lo, a1hi, ah1, al1);
#pragma unroll
            for (int t = 0; t < 4; ++t) {
                acc[0][t] = mfma16(ah0, bh[t], acc[0][t]);
                acc[0][t] = mfma16(ah0, bl[t], acc[0][t]);
                acc[0][t] = mfma16(al0, bh[t], acc[0][t]);
                acc[1][t] = mfma16(ah1, bh[t], acc[1][t]);
                acc[1][t] = mfma16(ah1, bl[t], acc[1][t]);
                acc[1][t] = mfma16(al1, bh[t], acc[1][t]);
            }
        }
        // ---- late ds_write of stage s+1 into the other buffer ----
        if (s + 1 < NSTAGE) {
#pragma unroll
            for (int i = 0; i < 4; ++i)
                *(f32x4*)(lds_raw + (buf ^ 1) * 16384 + (srow + 8 * i) * 512 +
                          ((scol * 16) ^ sw)) = areg[i];
        }
        __syncthreads();
    }

    // ---- cross-wave K-reduction via reused LDS (exactly 32 KB) ----
    // C/D layout: col = lane&15, row = (lane>>4)*4 + reg   [m89-verified]
    float(*red)[32][64] = (float(*)[32][64])lds_raw;
#pragma unroll
    for (int g = 0; g < 2; ++g)
#pragma unroll
        for (int t = 0; t < 4; ++t)
#pragma unroll
            for (int r = 0; r < 4; ++r)
                red[wv][g * 16 + kq * 4 + r][t * 16 + rq] = acc[g][t][r];
    __syncthreads();

    const int row = tid >> 3;
    const int c0 = (tid & 7) * 8;
    f32x4 s0 = f32x4{0.f, 0.f, 0.f, 0.f};
    f32x4 s1 = f32x4{0.f, 0.f, 0.f, 0.f};
#pragma unroll
    for (int w = 0; w < 4; ++w) {
        s0 += *(const f32x4*)&red[w][row][c0];
        s1 += *(const f32x4*)&red[w][row][c0 + 4];
    }
    float* pp = partial + (size_t)ks * (NROWS * HID) + (size_t)(rbase + row) * HID + c0;
    __builtin_nontemporal_store(s0, (f32x4*)pp);
    __builtin_nontemporal_store(s1, (f32x4*)(pp + 4));
}

// ---------------------------------------------------------------------------
// reduce_dense: agg_r = sum_ks partial[ks][r]; x_out[r] = tanh([agg_r|x_r] @ W)
// W [128,64] staged in LDS; lane = output column; row values via __shfl.
// ---------------------------------------------------------------------------
__global__ __launch_bounds__(256) void reduce_dense(const float* __restrict__ partial,
                                                    const float* __restrict__ xin,
                                                    const float* __restrict__ W,
                                                    float* __restrict__ xout) {
    __shared__ float wsm[128 * 64];  // 32 KB
    const f32x4* wsrc = (const f32x4*)W;
    f32x4* wdst = (f32x4*)wsm;
#pragma unroll
    for (int i = 0; i < 8; ++i) wdst[threadIdx.x + 256 * i] = wsrc[threadIdx.x + 256 * i];
    __syncthreads();

    const int lane = threadIdx.x & 63;
    const int wv = threadIdx.x >> 6;
    const int r0 = blockIdx.x * 32 + wv * 8;
#pragma unroll 2
    for (int i = 0; i < 8; ++i) {
        const int r = r0 + i;
        float av = 0.f;
#pragma unroll
        for (int ks = 0; ks < KSPLIT; ++ks)
            av += partial[(size_t)ks * (NROWS * HID) + (size_t)r * HID + lane];
        const float xv = xin[(size_t)r * HID + lane];
        float z = 0.f;
#pragma unroll
        for (int j = 0; j < 64; ++j) z += __shfl(av, j) * wsm[j * 64 + lane];
#pragma unroll
        for (int j = 0; j < 64; ++j) z += __shfl(xv, j) * wsm[(64 + j) * 64 + lane];
        xout[(size_t)r * HID + lane] = tanhf(z);
    }
}

extern "C" void kernel_launch(void* const* d_in, const int* in_sizes, int n_in,
                              void* d_out, int out_size, void* d_ws, size_t ws_size,
                              hipStream_t stream) {
    const float* x0 = (const float*)d_in[0];   // user_embs [16384,64]
    const float* adj = (const float*)d_in[1];  // adj [16384,16384]
    const float* W = (const float*)d_in[2];    // W [2,128,64]
    float* out = (float*)d_out;

    char* ws = (char*)d_ws;
    __bf16* Bhi = (__bf16*)(ws);                       // 2 MB
    __bf16* Blo = (__bf16*)(ws + (2u << 20));          // 2 MB
    float* partial = (float*)(ws + (4u << 20));        // 32 MB (8 x 4 MB)
    float* x1 = (float*)(ws + (36u << 20));            // 4 MB

    // hop 0
    pack_b<<<512, 256, 0, stream>>>(x0, Bhi, Blo);
    gemm_partial<<<KSPLIT * 512, 256, 0, stream>>>(adj, Bhi, Blo, partial);
    reduce_dense<<<512, 256, 0, stream>>>(partial, x0, W, x1);
    // hop 1
    pack_b<<<512, 256, 0, stream>>>(x1, Bhi, Blo);
    gemm_partial<<<KSPLIT * 512, 256, 0, stream>>>(adj, Bhi, Blo, partial);
    reduce_dense<<<512, 256, 0, stream>>>(partial, x1, W + 128 * 64, out);
}